// Round 1
// 186.686 us; speedup vs baseline: 1.0220x; 1.0220x over previous
//
#include <hip/hip_runtime.h>

typedef unsigned short ushort_t;
typedef unsigned int uint32;
typedef __attribute__((ext_vector_type(8))) short s16x8;   // 8 bf16 in 4 VGPRs
typedef __attribute__((ext_vector_type(4))) float f32x4;   // MFMA accumulator

#define BB   16
#define CC   256
#define NPX  4096          // 64*64 pixels
#define EE   4
#define HID  128
#define RHH  128
#define PW   66            // padded image width
#define PPX  (66*66)       // padded pixels per image

__device__ __forceinline__ ushort_t f2bf(float f) {
  uint32 x = __float_as_uint(f);
  x += 0x7fffu + ((x >> 16) & 1u);           // round-to-nearest-even
  return (ushort_t)(x >> 16);
}
// async global->LDS, 16B per lane; lds ptr wave-uniform (HW adds lane*16)
__device__ __forceinline__ void g2l16(const void* g, void* l) {
  __builtin_amdgcn_global_load_lds((const __attribute__((address_space(1))) uint32*)g,
                                   (__attribute__((address_space(3))) uint32*)l, 16, 0, 0);
}

// ---------- prep: pooling (direct, coalesced) + weight prep + y1 pad ring ----------
__global__ __launch_bounds__(256)
void k_prep(const float* __restrict__ x, float* __restrict__ pooled,
            const float* __restrict__ W1f, const float* __restrict__ W3f,
            const float* __restrict__ W2f, ushort_t* __restrict__ W1b,
            ushort_t* __restrict__ W3b, ushort_t* __restrict__ W2r,
            ushort_t* __restrict__ y1Tp) {
  int bid = blockIdx.x, t = threadIdx.x;
  if (bid < 4096) {           // pooling: one block per (b,c), 16KB contiguous read
    int c = bid & 255, b = bid >> 8;
    const float* xg = x + ((size_t)b * CC + c) * NPX;
    float s = 0.f;
#pragma unroll
    for (int k = 0; k < 4; ++k) {
      float4 v = *(const float4*)(xg + (size_t)(k * 256 + t) * 4);
      s += v.x + v.y + v.z + v.w;
    }
#pragma unroll
    for (int o = 32; o >= 1; o >>= 1) s += __shfl_down(s, o, 64);
    __shared__ float wsum[4];
    if ((t & 63) == 0) wsum[t >> 6] = s;
    __syncthreads();
    if (t == 0) pooled[(size_t)b * CC + c] = wsum[0] + wsum[1] + wsum[2] + wsum[3];
  } else if (bid < 4352) {    // W1/W3 convert, 4 elems/thread
    int i4 = ((bid - 4096) * 256 + t) * 4;
    const float* src; ushort_t* dst; int off;
    if (i4 < EE * HID * CC) { src = W1f; dst = W1b; off = i4; }
    else { src = W3f; dst = W3b; off = i4 - EE * HID * CC; }
    float4 v = *(const float4*)(src + off);
    ushort4 o;
    o.x = f2bf(v.x); o.y = f2bf(v.y); o.z = f2bf(v.z); o.w = f2bf(v.w);
    *(ushort4*)(dst + off) = o;
  } else if (bid < 6656) {    // W2 repack+convert, 1 elem/thread
    int i = (bid - 4352) * 256 + t;   // i = ((e*9+tap)*128+g)*128+h
    int h = i & 127;
    int g = (i >> 7) & 127;
    int et = i >> 14;
    int tap = et % 9;
    int e = et / 9;
    W2r[i] = f2bf(W2f[((((size_t)e * 128 + g) * 128 + h) * 3 + tap / 3) * 3 + tap % 3]);
  } else {                    // y1 pad ring: 260 pad px/batch, 128ch, zero
    int p = (bid - 6656) * 8 + (t >> 5);      // pad-pixel index, 32 lanes each
    int b = p / 260, i = p % 260;
    int row, col;
    if (i < 66)       { row = 0;       col = i; }
    else if (i < 132) { row = 65;      col = i - 66; }
    else if (i < 196) { row = i - 131; col = 0; }
    else              { row = i - 195; col = 65; }
    uint2* dst = (uint2*)(y1Tp + (((size_t)b * PPX + row * PW + col) * HID) + (t & 31) * 4);
    *dst = make_uint2(0u, 0u);
  }
}

// ---------- router: MLP + softmax + top-1 (fp32) ----------
__global__ __launch_bounds__(128)
void k_router(const float* __restrict__ pooled, const float* __restrict__ Wr1,
              const float* __restrict__ br1, const float* __restrict__ Wr2,
              const float* __restrict__ br2, int* __restrict__ eidx,
              float* __restrict__ gatew) {
  int b = blockIdx.x, t = threadIdx.x;
  __shared__ float spool[CC];
  __shared__ float hb[RHH];
  __shared__ float lg[EE];
  for (int cc = t; cc < CC; cc += 128) spool[cc] = pooled[(size_t)b * CC + cc];
  __syncthreads();
  float s0 = 0.f;
  const float* wr = Wr1 + t * CC;
  for (int c = 0; c < CC; ++c) s0 += spool[c] * wr[c];
  float a = br1[t] + s0 * (1.0f / NPX);
  hb[t] = a > 0.f ? a : 0.f;
  __syncthreads();
  if (t < EE) {
    float s = br2[t];
    const float* w2 = Wr2 + t * RHH;
    for (int r = 0; r < RHH; ++r) s += hb[r] * w2[r];
    lg[t] = s;
  }
  __syncthreads();
  if (t == 0) {
    float m = lg[0]; int mi = 0;
    for (int e = 1; e < EE; ++e) if (lg[e] > m) { m = lg[e]; mi = e; }  // first-max = lax.top_k tie rule
    float den = 0.f;
    for (int e = 0; e < EE; ++e) den += expf(lg[e] - m);
    float v = 1.0f / den;                 // softmax value at argmax
    eidx[b] = mi;
    gatew[b] = v / (v + 1e-9f);           // top-1 renormalized weight
  }
}

// BK=64 tile: rows are 128B; 16B chunks XOR-swizzled (chunk^row&7) so that
// ds_read_b128 fragment reads spread across banks. Swizzle applied on the
// GLOBAL address side of global_load_lds (its LDS side is fixed lane*16).
#define STAGE64(dstA, srcA_expr, dstB, srcB_expr)                         \
  {                                                                       \
    _Pragma("unroll")                                                     \
    for (int s_ = 0; s_ < 4; ++s_) {                                      \
      int ch_ = wave * 4 + s_;                                            \
      int r = ch_ * 8 + (lane >> 3);                                      \
      int kc = ((lane & 7) ^ (lane >> 3)) * 8;                            \
      g2l16(srcA_expr, &dstA[ch_ * 512]);                                 \
      g2l16(srcB_expr, &dstB[ch_ * 512]);                                 \
    }                                                                     \
  }

#define STAGE64B(dstB, srcB_expr)                                         \
  {                                                                       \
    _Pragma("unroll")                                                     \
    for (int s_ = 0; s_ < 4; ++s_) {                                      \
      int ch_ = wave * 4 + s_;                                            \
      int r = ch_ * 8 + (lane >> 3);                                      \
      int kc = ((lane & 7) ^ (lane >> 3)) * 8;                            \
      g2l16(srcB_expr, &dstB[ch_ * 512]);                                 \
    }                                                                     \
  }

#define MFMA64(At_, Bt_, ACC_)                                            \
  _Pragma("unroll")                                                       \
  for (int kh = 0; kh < 2; ++kh) {                                        \
    s16x8 af[4], bfr[4];                                                  \
    int cidx = ((kh * 4 + (lane >> 4)) ^ (lane & 7)) * 8;                 \
    _Pragma("unroll")                                                     \
    for (int i = 0; i < 4; ++i)                                           \
      af[i] = *(const s16x8*)&At_[(wm + i * 16 + (lane & 15)) * 64 + cidx]; \
    _Pragma("unroll")                                                     \
    for (int j = 0; j < 4; ++j)                                           \
      bfr[j] = *(const s16x8*)&Bt_[(wn + j * 16 + (lane & 15)) * 64 + cidx]; \
    _Pragma("unroll")                                                     \
    for (int i = 0; i < 4; ++i)                                           \
      _Pragma("unroll")                                                   \
      for (int j = 0; j < 4; ++j)                                         \
        ACC_[i][j] = __builtin_amdgcn_mfma_f32_16x16x32_bf16(af[i], bfr[j], ACC_[i][j], 0, 0, 0); \
  }

// ---------- conv1: fused x-transpose (fp32->bf16, in-register) + 1x1 C->HID ----------
// A tile is built by reading x [c][px] fp32 directly (rows L3-hot from k_prep),
// packing channel-pairs to u32 bf16x2 and ds_write_b32 into the swizzled layout
// MFMA64 expects. Epilogue stages the 128px x 128h tile in LDS (aliasing At/Bt)
// and writes y1 as full 256B pixel rows, 16B/lane (1KB contiguous per wave instr).
__global__ __launch_bounds__(256)
void k_conv1(const float* __restrict__ x, const ushort_t* __restrict__ W1b,
             const int* __restrict__ eidx, ushort_t* __restrict__ y1Tp) {
  int mt = blockIdx.x, b = blockIdx.y;
  int e = eidx[b];
  int t = threadIdx.x, wave = t >> 6, lane = t & 63;
  int wm = (wave & 1) * 64, wn = (wave >> 1) * 64;
  __shared__ ushort_t smem[128 * 128];     // 32K: At(16K)+Bt(16K); epilogue tile alias
  ushort_t* At = smem;
  ushort_t* Bt = smem + 128 * 64;
  f32x4 acc[4][4] = {};
  const float* xg = x + (size_t)b * CC * NPX + mt * 128;
  const ushort_t* w1 = W1b + (size_t)e * HID * CC;

  int cp = t >> 3;              // channel-pair 0..31
  int kk = cp * 2;              // k index within 64-wide K tile
  int pxb = (t & 7) * 4;        // px base: lanes 0-7 cover 128B contiguous per row

  for (int ks = 0; ks < 4; ++ks) {
    int k0 = ks * 64;
    __syncthreads();
    STAGE64B(Bt, w1 + (size_t)r * CC + k0 + kc);
    {   // A transpose: 2 c-rows x 16 px fp32 -> bf16x2 -> swizzled ds_write
      const float* r0 = xg + (size_t)(k0 + kk) * NPX;
      const float* r1 = r0 + NPX;
#pragma unroll
      for (int i = 0; i < 4; ++i) {
        int p = pxb + i * 32;
        float4 va = *(const float4*)(r0 + p);
        float4 vb = *(const float4*)(r1 + p);
#pragma unroll
        for (int q = 0; q < 4; ++q) {
          int m = p + q;
          uint32 v = (uint32)f2bf(((const float*)&va)[q]) |
                     ((uint32)f2bf(((const float*)&vb)[q]) << 16);
          int us = m * 64 + (((kk >> 3) ^ (m & 7)) << 3) + (kk & 7);
          *(uint32*)&At[us] = v;
        }
      }
    }
    __syncthreads();
    MFMA64(At, Bt, acc);
  }
  // epilogue: relu+cvt -> swizzled LDS tile -> coalesced 16B/lane y1 writes
  __syncthreads();
#pragma unroll
  for (int i = 0; i < 4; ++i)
#pragma unroll
    for (int j = 0; j < 4; ++j)
#pragma unroll
      for (int r = 0; r < 4; ++r) {
        int m = wm + i * 16 + (lane >> 4) * 4 + r;
        int n = wn + j * 16 + (lane & 15);
        float v = acc[i][j][r];
        smem[m * 128 + (((n >> 3) ^ (m & 7)) << 3) + (n & 7)] = f2bf(v > 0.f ? v : 0.f);
      }
  __syncthreads();
  ushort_t* yb = y1Tp + (size_t)b * PPX * HID;
#pragma unroll
  for (int it = 0; it < 8; ++it) {
    int idx = it * 256 + t;
    int row = idx >> 4, ch = idx & 15;
    int prow = mt * 2 + (row >> 6) + 1, pcol = (row & 63) + 1;
    uint4 v = *(const uint4*)&smem[row * 128 + ((ch ^ (row & 7)) << 3)];
    *(uint4*)(yb + ((size_t)prow * PW + pcol) * HID + ch * 8) = v;
  }
}

// ---------- fused conv2 (3x3 HID->HID) + conv3 (1x1 HID->C) + gate + residual ----------
// Phase 1: conv2 into acc (y2 tile 128px x 128h stays on-chip)
// Phase 2: relu+cvt acc -> swizzled LDS y2 tile (same layout MFMA64 reads)
// Phase 3: conv3, N=256 in two halves, K=128 from LDS y2
// Phase 4: LDS-coalesced fp32 epilogue (gw*acc3 + x -> out)
__global__ __launch_bounds__(256, 2)
void k_conv23(const ushort_t* __restrict__ y1Tp, const ushort_t* __restrict__ W2r,
              const ushort_t* __restrict__ W3b, const float* __restrict__ x,
              const int* __restrict__ eidx, const float* __restrict__ gatew,
              float* __restrict__ out) {
  int mt = blockIdx.x, b = blockIdx.y;
  int e = eidx[b];
  float gw = gatew[b];
  int t = threadIdx.x, wave = t >> 6, lane = t & 63;
  int wm = (wave & 1) * 64, wn = (wave >> 1) * 64;
  __shared__ ushort_t bufA[128 * 64];     // 16K: conv2 A-staging; conv3 W3 (ks=0)
  __shared__ ushort_t bufB[128 * 64];     // 16K: conv2 B-staging; conv3 W3 (ks=1)
  __shared__ ushort_t y2s[2][128 * 64];   // 32K: y2 tile (k-halves); epilogue Tf alias
  const ushort_t* yb = y1Tp + (size_t)b * PPX * HID;
  const ushort_t* w2e = W2r + (size_t)e * 9 * HID * HID;

  // ---- phase 1: conv2 ----
  f32x4 acc[4][4] = {};
  for (int tap = 0; tap < 9; ++tap) {
    int dy = tap / 3 - 1, dx = tap % 3 - 1;
    const ushort_t* w2t = w2e + tap * HID * HID;
#pragma unroll
    for (int ks = 0; ks < 2; ++ks) {
      int k0 = ks * 64;
      __syncthreads();
      STAGE64(bufA, yb + ((size_t)(mt * 2 + (r >> 6) + 1 + dy) * PW + (r & 63) + 1 + dx) * HID + k0 + kc,
              bufB, w2t + (size_t)r * HID + k0 + kc);
      __syncthreads();
      MFMA64(bufA, bufB, acc);
    }
  }
  // ---- phase 2: relu+cvt -> swizzled y2 LDS tile (each wave writes its own region) ----
#pragma unroll
  for (int i = 0; i < 4; ++i)
#pragma unroll
    for (int j = 0; j < 4; ++j)
#pragma unroll
      for (int r = 0; r < 4; ++r) {
        int m = wm + i * 16 + (lane >> 4) * 4 + r;
        int n = wn + j * 16 + (lane & 15);
        float v = acc[i][j][r];
        ushort_t bv = f2bf(v > 0.f ? v : 0.f);
        int nn = n & 63;
        ushort_t* buf = (n < 64) ? y2s[0] : y2s[1];   // wave-uniform select
        buf[m * 64 + ((nn >> 3) ^ (m & 7)) * 8 + (nn & 7)] = bv;
      }
  __syncthreads();
  // ---- phase 3: conv3, both 128-c halves, K=128 from y2s ----
  f32x4 acc3[2][4][4] = {};
  const ushort_t* w3 = W3b + (size_t)e * CC * HID;
#pragma unroll
  for (int h = 0; h < 2; ++h) {
#pragma unroll
    for (int ks = 0; ks < 2; ++ks) {
      ushort_t* bt = (ks == 0) ? bufA : bufB;
      STAGE64B(bt, w3 + (size_t)(h * 128 + r) * HID + ks * 64 + kc);
      __syncthreads();
      MFMA64(y2s[ks], bt, acc3[h]);
      // next STAGE64B overwrites only after all waves passed the barrier above,
      // and each wave's LDS reads complete before its own MFMAs -> WAR safe
    }
  }
  // ---- phase 4: coalesced epilogue, Tf aliases y2s (dead now) ----
  float* Tf = (float*)y2s;   // 32c x 128px, pitch 132 (16.9 KB < 32 KB)
  for (int h = 0; h < 2; ++h) {
    for (int jj = 0; jj < 4; ++jj) {
      __syncthreads();
      if ((wn >> 6) == (jj >> 1)) {     // the 2 waves holding this c-range
        int j0 = (jj & 1) * 2;
#pragma unroll
        for (int jd = 0; jd < 2; ++jd) {
          int cl = jd * 16 + (lane & 15);
#pragma unroll
          for (int i = 0; i < 4; ++i) {
            int pb = wm + i * 16 + (lane >> 4) * 4;
            *(f32x4*)&Tf[cl * 132 + pb] = acc3[h][i][j0 + jd];
          }
        }
      }
      __syncthreads();
#pragma unroll
      for (int it = 0; it < 4; ++it) {
        int idx = it * 256 + t;          // 0..1023
        int crow = idx >> 5;             // 0..31
        int p4 = (idx & 31) * 4;
        int c = h * 128 + jj * 32 + crow;
        int px = mt * 128 + p4;
        size_t base = ((size_t)b * CC + c) * NPX + px;
        f32x4 vv = *(const f32x4*)&Tf[crow * 132 + p4];
        f32x4 xa = *(const f32x4*)(x + base);
        vv = gw * vv + xa;
        __builtin_nontemporal_store(vv, (f32x4*)(out + base));
      }
    }
  }
}

extern "C" void kernel_launch(void* const* d_in, const int* in_sizes, int n_in,
                              void* d_out, int out_size, void* d_ws, size_t ws_size,
                              hipStream_t stream) {
  const float* x   = (const float*)d_in[0];
  const float* Wr1 = (const float*)d_in[1];
  const float* br1 = (const float*)d_in[2];
  const float* Wr2 = (const float*)d_in[3];
  const float* br2 = (const float*)d_in[4];
  const float* W1  = (const float*)d_in[5];
  const float* W2  = (const float*)d_in[6];
  const float* W3  = (const float*)d_in[7];
  float* out = (float*)d_out;

  char* ws = (char*)d_ws;
  int*      eidx   = (int*)ws;                         // 64 B
  float*    gatew  = (float*)(ws + 64);                // 64 B -> 256
  float*    pooled = (float*)(ws + 256);               // 16 KB -> 16640
  ushort_t* W1b    = (ushort_t*)(ws + 16640);          // 256 KB -> 278784
  ushort_t* W3b    = (ushort_t*)(ws + 278784);         // 256 KB -> 540928
  ushort_t* W2r    = (ushort_t*)(ws + 540928);         // 1.125 MB -> 1720576
  ushort_t* y1Tp   = (ushort_t*)(ws + 1720576);        // 17.0 MB -> ~19.6 MB total

  k_prep  <<<7176, 256, 0, stream>>>(x, pooled, W1, W3, W2, W1b, W3b, W2r, y1Tp);
  k_router<<<16, 128, 0, stream>>>(pooled, Wr1, br1, Wr2, br2, eidx, gatew);
  k_conv1 <<<dim3(32, 16), 256, 0, stream>>>(x, W1b, eidx, y1Tp);
  k_conv23<<<dim3(32, 16), 256, 0, stream>>>(y1Tp, W2r, W3b, x, eidx, gatew, out);
}

// Round 2
// 184.747 us; speedup vs baseline: 1.0327x; 1.0105x over previous
//
#include <hip/hip_runtime.h>

typedef unsigned short ushort_t;
typedef unsigned int uint32;
typedef __attribute__((ext_vector_type(8))) short s16x8;   // 8 bf16 in 4 VGPRs
typedef __attribute__((ext_vector_type(4))) float f32x4;   // MFMA accumulator

#define BB   16
#define CC   256
#define NPX  4096          // 64*64 pixels
#define EE   4
#define HID  128
#define RHH  128
#define PW   66            // padded image width
#define PPX  (66*66)       // padded pixels per image

__device__ __forceinline__ ushort_t f2bf(float f) {
  uint32 x = __float_as_uint(f);
  x += 0x7fffu + ((x >> 16) & 1u);           // round-to-nearest-even
  return (ushort_t)(x >> 16);
}
// async global->LDS, 16B per lane; lds ptr wave-uniform (HW adds lane*16)
__device__ __forceinline__ void g2l16(const void* g, void* l) {
  __builtin_amdgcn_global_load_lds((const __attribute__((address_space(1))) uint32*)g,
                                   (__attribute__((address_space(3))) uint32*)l, 16, 0, 0);
}

// ---------- prep: pooling (direct, coalesced) + weight prep + y1 pad ring ----------
__global__ __launch_bounds__(256)
void k_prep(const float* __restrict__ x, float* __restrict__ pooled,
            const float* __restrict__ W1f, const float* __restrict__ W3f,
            const float* __restrict__ W2f, ushort_t* __restrict__ W1b,
            ushort_t* __restrict__ W3b, ushort_t* __restrict__ W2r,
            ushort_t* __restrict__ y1Tp) {
  int bid = blockIdx.x, t = threadIdx.x;
  if (bid < 4096) {           // pooling: one block per (b,c), 16KB contiguous read
    int c = bid & 255, b = bid >> 8;
    const float* xg = x + ((size_t)b * CC + c) * NPX;
    float s = 0.f;
#pragma unroll
    for (int k = 0; k < 4; ++k) {
      float4 v = *(const float4*)(xg + (size_t)(k * 256 + t) * 4);
      s += v.x + v.y + v.z + v.w;
    }
#pragma unroll
    for (int o = 32; o >= 1; o >>= 1) s += __shfl_down(s, o, 64);
    __shared__ float wsum[4];
    if ((t & 63) == 0) wsum[t >> 6] = s;
    __syncthreads();
    if (t == 0) pooled[(size_t)b * CC + c] = wsum[0] + wsum[1] + wsum[2] + wsum[3];
  } else if (bid < 4352) {    // W1/W3 convert, 4 elems/thread
    int i4 = ((bid - 4096) * 256 + t) * 4;
    const float* src; ushort_t* dst; int off;
    if (i4 < EE * HID * CC) { src = W1f; dst = W1b; off = i4; }
    else { src = W3f; dst = W3b; off = i4 - EE * HID * CC; }
    float4 v = *(const float4*)(src + off);
    ushort4 o;
    o.x = f2bf(v.x); o.y = f2bf(v.y); o.z = f2bf(v.z); o.w = f2bf(v.w);
    *(ushort4*)(dst + off) = o;
  } else if (bid < 4480) {    // W2 repack: contiguous 72B reads, u32 coalesced stores
    int idx = (bid - 4352) * 256 + t;     // 0..32767 = (e*128+o)*64 + ip/2
    int e = idx >> 13;
    int o = (idx >> 6) & 127;
    int ip = (idx & 63) * 2;
    const float* s0 = W2f + ((size_t)((e * 128 + o) * 128) + ip) * 9;
    float v0[9], v1[9];
#pragma unroll
    for (int tp = 0; tp < 9; ++tp) { v0[tp] = s0[tp]; v1[tp] = s0[9 + tp]; }
#pragma unroll
    for (int tp = 0; tp < 9; ++tp) {
      uint32 w = (uint32)f2bf(v0[tp]) | ((uint32)f2bf(v1[tp]) << 16);
      *(uint32*)&W2r[(((size_t)(e * 9 + tp) * 128 + o) * 128) + ip] = w;
    }
  } else {                    // y1 pad ring: 260 pad px/batch, 128ch, zero
    int p = (bid - 4480) * 8 + (t >> 5);      // pad-pixel index, 32 lanes each
    int b = p / 260, i = p % 260;
    int row, col;
    if (i < 66)       { row = 0;       col = i; }
    else if (i < 132) { row = 65;      col = i - 66; }
    else if (i < 196) { row = i - 131; col = 0; }
    else              { row = i - 195; col = 65; }
    uint2* dst = (uint2*)(y1Tp + (((size_t)b * PPX + row * PW + col) * HID) + (t & 31) * 4);
    *dst = make_uint2(0u, 0u);
  }
}

// ---------- router: MLP + softmax + top-1 (fp32) ----------
__global__ __launch_bounds__(128)
void k_router(const float* __restrict__ pooled, const float* __restrict__ Wr1,
              const float* __restrict__ br1, const float* __restrict__ Wr2,
              const float* __restrict__ br2, int* __restrict__ eidx,
              float* __restrict__ gatew) {
  int b = blockIdx.x, t = threadIdx.x;
  __shared__ float spool[CC];
  __shared__ float hb[RHH];
  __shared__ float lg[EE];
  for (int cc = t; cc < CC; cc += 128) spool[cc] = pooled[(size_t)b * CC + cc];
  __syncthreads();
  float s0 = 0.f;
  const float* wr = Wr1 + t * CC;
  for (int c = 0; c < CC; ++c) s0 += spool[c] * wr[c];
  float a = br1[t] + s0 * (1.0f / NPX);
  hb[t] = a > 0.f ? a : 0.f;
  __syncthreads();
  if (t < EE) {
    float s = br2[t];
    const float* w2 = Wr2 + t * RHH;
    for (int r = 0; r < RHH; ++r) s += hb[r] * w2[r];
    lg[t] = s;
  }
  __syncthreads();
  if (t == 0) {
    float m = lg[0]; int mi = 0;
    for (int e = 1; e < EE; ++e) if (lg[e] > m) { m = lg[e]; mi = e; }  // first-max = lax.top_k tie rule
    float den = 0.f;
    for (int e = 0; e < EE; ++e) den += expf(lg[e] - m);
    float v = 1.0f / den;                 // softmax value at argmax
    eidx[b] = mi;
    gatew[b] = v / (v + 1e-9f);           // top-1 renormalized weight
  }
}

// BK=64 tile staging: rows are 128B; 16B chunks XOR-swizzled (chunk^row&7) so
// ds_read_b128 fragment reads spread across banks. Swizzle applied on the
// GLOBAL address side of global_load_lds (its LDS side is fixed lane*16).
#define STAGE64B(dstB, srcB_expr)                                         \
  {                                                                       \
    _Pragma("unroll")                                                     \
    for (int s_ = 0; s_ < 4; ++s_) {                                      \
      int ch_ = wave * 4 + s_;                                            \
      int r = ch_ * 8 + (lane >> 3);                                      \
      int kc = ((lane & 7) ^ (lane >> 3)) * 8;                            \
      g2l16(srcB_expr, &dstB[ch_ * 512]);                                 \
    }                                                                     \
  }

// weight-tile stage: 128 rows x 64 k from wsrc (row stride HID), k offset k0v
#define STAGEW(dst, wsrc, k0v)                                            \
  {                                                                       \
    _Pragma("unroll")                                                     \
    for (int s_ = 0; s_ < 4; ++s_) {                                      \
      int ch_ = wave * 4 + s_;                                            \
      int r_ = ch_ * 8 + (lane >> 3);                                     \
      int kc_ = ((lane & 7) ^ (lane >> 3)) * 8;                           \
      g2l16(wsrc + (size_t)r_ * HID + (k0v) + kc_, &dst[ch_ * 512]);      \
    }                                                                     \
  }

#define MFMA64(At_, Bt_, ACC_)                                            \
  _Pragma("unroll")                                                       \
  for (int kh = 0; kh < 2; ++kh) {                                        \
    s16x8 af[4], bfr[4];                                                  \
    int cidx = ((kh * 4 + (lane >> 4)) ^ (lane & 7)) * 8;                 \
    _Pragma("unroll")                                                     \
    for (int i = 0; i < 4; ++i)                                           \
      af[i] = *(const s16x8*)&At_[(wm + i * 16 + (lane & 15)) * 64 + cidx]; \
    _Pragma("unroll")                                                     \
    for (int j = 0; j < 4; ++j)                                           \
      bfr[j] = *(const s16x8*)&Bt_[(wn + j * 16 + (lane & 15)) * 64 + cidx]; \
    _Pragma("unroll")                                                     \
    for (int i = 0; i < 4; ++i)                                           \
      _Pragma("unroll")                                                   \
      for (int j = 0; j < 4; ++j)                                         \
        ACC_[i][j] = __builtin_amdgcn_mfma_f32_16x16x32_bf16(af[i], bfr[j], ACC_[i][j], 0, 0, 0); \
  }

// A from resident halo Hs[4][66][64] (pixel-major, chunk-XOR key = pixidx&7)
#define MFMA64H(Hs_, dyv, dxv, Bt_, ACC_)                                 \
  {                                                                       \
    int hbase = ((wm >> 6) + 1 + (dyv)) * 66 + (lane & 15) + 1 + (dxv);   \
    _Pragma("unroll")                                                     \
    for (int kh = 0; kh < 2; ++kh) {                                      \
      s16x8 af[4], bfr[4];                                                \
      int clog = kh * 4 + (lane >> 4);                                    \
      int aoff = (clog ^ (hbase & 7)) << 3;                               \
      int cidx = (clog ^ (lane & 7)) << 3;                                \
      _Pragma("unroll")                                                   \
      for (int i = 0; i < 4; ++i)                                         \
        af[i] = *(const s16x8*)&Hs_[(hbase + i * 16) * 64 + aoff];        \
      _Pragma("unroll")                                                   \
      for (int j = 0; j < 4; ++j)                                         \
        bfr[j] = *(const s16x8*)&Bt_[(wn + j * 16 + (lane & 15)) * 64 + cidx]; \
      _Pragma("unroll")                                                   \
      for (int i = 0; i < 4; ++i)                                         \
        _Pragma("unroll")                                                 \
        for (int j = 0; j < 4; ++j)                                       \
          ACC_[i][j] = __builtin_amdgcn_mfma_f32_16x16x32_bf16(af[i], bfr[j], ACC_[i][j], 0, 0, 0); \
    }                                                                     \
  }

// ---------- conv1: fused x-transpose (fp32->bf16, in-register) + 1x1 C->HID ----------
__global__ __launch_bounds__(256)
void k_conv1(const float* __restrict__ x, const ushort_t* __restrict__ W1b,
             const int* __restrict__ eidx, ushort_t* __restrict__ y1Tp) {
  int mt = blockIdx.x, b = blockIdx.y;
  int e = eidx[b];
  int t = threadIdx.x, wave = t >> 6, lane = t & 63;
  int wm = (wave & 1) * 64, wn = (wave >> 1) * 64;
  __shared__ ushort_t smem[128 * 128];     // 32K: At(16K)+Bt(16K); epilogue tile alias
  ushort_t* At = smem;
  ushort_t* Bt = smem + 128 * 64;
  f32x4 acc[4][4] = {};
  const float* xg = x + (size_t)b * CC * NPX + mt * 128;
  const ushort_t* w1 = W1b + (size_t)e * HID * CC;

  int cp = t >> 3;              // channel-pair 0..31
  int kk = cp * 2;              // k index within 64-wide K tile
  int pxb = (t & 7) * 4;        // px base: lanes 0-7 cover 128B contiguous per row

  for (int ks = 0; ks < 4; ++ks) {
    int k0 = ks * 64;
    __syncthreads();
    STAGE64B(Bt, w1 + (size_t)r * CC + k0 + kc);
    {   // A transpose: 2 c-rows x 16 px fp32 -> bf16x2 -> swizzled ds_write
      const float* r0 = xg + (size_t)(k0 + kk) * NPX;
      const float* r1 = r0 + NPX;
#pragma unroll
      for (int i = 0; i < 4; ++i) {
        int p = pxb + i * 32;
        float4 va = *(const float4*)(r0 + p);
        float4 vb = *(const float4*)(r1 + p);
#pragma unroll
        for (int q = 0; q < 4; ++q) {
          int m = p + q;
          uint32 v = (uint32)f2bf(((const float*)&va)[q]) |
                     ((uint32)f2bf(((const float*)&vb)[q]) << 16);
          int us = m * 64 + (((kk >> 3) ^ (m & 7)) << 3) + (kk & 7);
          *(uint32*)&At[us] = v;
        }
      }
    }
    __syncthreads();
    MFMA64(At, Bt, acc);
  }
  // epilogue: relu+cvt -> swizzled LDS tile -> coalesced 16B/lane y1 writes
  __syncthreads();
#pragma unroll
  for (int i = 0; i < 4; ++i)
#pragma unroll
    for (int j = 0; j < 4; ++j)
#pragma unroll
      for (int r = 0; r < 4; ++r) {
        int m = wm + i * 16 + (lane >> 4) * 4 + r;
        int n = wn + j * 16 + (lane & 15);
        float v = acc[i][j][r];
        smem[m * 128 + (((n >> 3) ^ (m & 7)) << 3) + (n & 7)] = f2bf(v > 0.f ? v : 0.f);
      }
  __syncthreads();
  ushort_t* yb = y1Tp + (size_t)b * PPX * HID;
#pragma unroll
  for (int it = 0; it < 8; ++it) {
    int idx = it * 256 + t;
    int row = idx >> 4, ch = idx & 15;
    int prow = mt * 2 + (row >> 6) + 1, pcol = (row & 63) + 1;
    uint4 v = *(const uint4*)&smem[row * 128 + ((ch ^ (row & 7)) << 3)];
    *(uint4*)(yb + ((size_t)prow * PW + pcol) * HID + ch * 8) = v;
  }
}

// ---------- fused conv2 (3x3) + conv3 (1x1) + gate + residual ----------
// Phase 1: resident y1 halo (33.8KB per K-half) + double-buffered W2 tiles with
//          counted vmcnt (loads in flight across barriers; no drain in tap loop)
// Phase 2: relu+cvt acc -> swizzled LDS y2 tile (aliases halo)
// Phase 3: conv3, N=256 in two halves, K=128 from LDS y2
// Phase 4: LDS-coalesced fp32 epilogue (gw*acc3 + x -> out)
__global__ __launch_bounds__(256, 2)
void k_conv23(const ushort_t* __restrict__ y1Tp, const ushort_t* __restrict__ W2r,
              const ushort_t* __restrict__ W3b, const float* __restrict__ x,
              const int* __restrict__ eidx, const float* __restrict__ gatew,
              float* __restrict__ out) {
  int mt = blockIdx.x, b = blockIdx.y;
  int e = eidx[b];
  float gw = gatew[b];
  int t = threadIdx.x, wave = t >> 6, lane = t & 63;
  int wm = (wave & 1) * 64, wn = (wave >> 1) * 64;
  __shared__ ushort_t Hs[4 * 66 * 64];    // 33.8K: y1 halo (per K-half); y2s/Tf alias later
  __shared__ ushort_t Wb0[128 * 64];      // 16K: W2 double-buffer / conv3 W3 (ks=0)
  __shared__ ushort_t Wb1[128 * 64];      // 16K: W2 double-buffer / conv3 W3 (ks=1)
  const ushort_t* yb = y1Tp + (size_t)b * PPX * HID;
  const ushort_t* w2e = W2r + (size_t)e * 9 * HID * HID;
  // force eidx/gatew loads complete before the counted-vmcnt loop
  asm volatile("" :: "v"(gw), "s"(e));

  // ---- phase 1: conv2, halo-resident A ----
  f32x4 acc[4][4] = {};
  for (int ks = 0; ks < 2; ++ks) {
    int k0 = ks * 64;
    __syncthreads();            // halo buffer free (prev reads done), drains vmem
    // stage halo: 2112 chunks of 16B; chunk q -> pixel p=q>>3, slot q&7
    // global src pre-swizzled (slot ^ (p&7)); LDS linear
#pragma unroll
    for (int it = 0; it < 9; ++it) {
      if (it < 8 || wave == 0) {
        int q = it * 256 + t;
        int p = q >> 3, slot = q & 7;
        g2l16(yb + ((size_t)(mt * 132 + p)) * HID + k0 + ((slot ^ (p & 7)) << 3),
              &Hs[(it * 256 + wave * 64) * 8]);
      }
    }
    STAGEW(Wb0, w2e + 0 * HID * HID, k0);          // tap 0
    __syncthreads();            // drains halo + B0 (vmcnt 0), all waves synced
#pragma unroll
    for (int tap = 0; tap < 9; ++tap) {
      ushort_t* cur = (tap & 1) ? Wb1 : Wb0;
      ushort_t* nxt = (tap & 1) ? Wb0 : Wb1;
      if (tap < 8) {
        STAGEW(nxt, w2e + (tap + 1) * HID * HID, k0);
        asm volatile("s_waitcnt vmcnt(4)" ::: "memory");   // my B[tap] chunks landed
      } else {
        asm volatile("s_waitcnt vmcnt(0)" ::: "memory");   // drain last tile
      }
      __builtin_amdgcn_s_barrier();                        // everyone's landed
      MFMA64H(Hs, tap / 3 - 1, tap % 3 - 1, cur, acc);
      __builtin_amdgcn_s_barrier();                        // reads done before overwrite
    }
  }
  // ---- phase 2: relu+cvt -> swizzled y2 LDS tile (aliases Hs; reads all done) ----
  ushort_t (*y2s)[128 * 64] = (ushort_t (*)[128 * 64])Hs;
#pragma unroll
  for (int i = 0; i < 4; ++i)
#pragma unroll
    for (int j = 0; j < 4; ++j)
#pragma unroll
      for (int r = 0; r < 4; ++r) {
        int m = wm + i * 16 + (lane >> 4) * 4 + r;
        int n = wn + j * 16 + (lane & 15);
        float v = acc[i][j][r];
        ushort_t bv = f2bf(v > 0.f ? v : 0.f);
        int nn = n & 63;
        ushort_t* buf = (n < 64) ? y2s[0] : y2s[1];   // wave-uniform select
        buf[m * 64 + ((nn >> 3) ^ (m & 7)) * 8 + (nn & 7)] = bv;
      }
  // ---- phase 3: conv3, both 128-c halves, K=128 from y2s ----
  f32x4 acc3[2][4][4] = {};
  const ushort_t* w3 = W3b + (size_t)e * CC * HID;
#pragma unroll
  for (int h = 0; h < 2; ++h) {
#pragma unroll
    for (int ks = 0; ks < 2; ++ks) {
      ushort_t* bt = (ks == 0) ? Wb0 : Wb1;
      STAGEW(bt, w3 + (size_t)h * 128 * HID, ks * 64);
      __syncthreads();          // drains stage + makes phase-2 y2s writes visible
      MFMA64(y2s[ks], bt, acc3[h]);
      // next STAGEW overwrites only after all waves passed the barrier above,
      // and each wave's LDS reads complete before its own MFMAs -> WAR safe
    }
  }
  // ---- phase 4: coalesced epilogue, Tf aliases Hs (dead now) ----
  float* Tf = (float*)Hs;   // 32c x 128px, pitch 132 (16.9 KB)
  for (int h = 0; h < 2; ++h) {
    for (int jj = 0; jj < 4; ++jj) {
      __syncthreads();
      if ((wn >> 6) == (jj >> 1)) {     // the 2 waves holding this c-range
        int j0 = (jj & 1) * 2;
#pragma unroll
        for (int jd = 0; jd < 2; ++jd) {
          int cl = jd * 16 + (lane & 15);
#pragma unroll
          for (int i = 0; i < 4; ++i) {
            int pb = wm + i * 16 + (lane >> 4) * 4;
            *(f32x4*)&Tf[cl * 132 + pb] = acc3[h][i][j0 + jd];
          }
        }
      }
      __syncthreads();
#pragma unroll
      for (int it = 0; it < 4; ++it) {
        int idx = it * 256 + t;          // 0..1023
        int crow = idx >> 5;             // 0..31
        int p4 = (idx & 31) * 4;
        int c = h * 128 + jj * 32 + crow;
        int px = mt * 128 + p4;
        size_t base = ((size_t)b * CC + c) * NPX + px;
        f32x4 vv = *(const f32x4*)&Tf[crow * 132 + p4];
        f32x4 xa = *(const f32x4*)(x + base);
        vv = gw * vv + xa;
        __builtin_nontemporal_store(vv, (f32x4*)(out + base));
      }
    }
  }
}

extern "C" void kernel_launch(void* const* d_in, const int* in_sizes, int n_in,
                              void* d_out, int out_size, void* d_ws, size_t ws_size,
                              hipStream_t stream) {
  const float* x   = (const float*)d_in[0];
  const float* Wr1 = (const float*)d_in[1];
  const float* br1 = (const float*)d_in[2];
  const float* Wr2 = (const float*)d_in[3];
  const float* br2 = (const float*)d_in[4];
  const float* W1  = (const float*)d_in[5];
  const float* W2  = (const float*)d_in[6];
  const float* W3  = (const float*)d_in[7];
  float* out = (float*)d_out;

  char* ws = (char*)d_ws;
  int*      eidx   = (int*)ws;                         // 64 B
  float*    gatew  = (float*)(ws + 64);                // 64 B -> 256
  float*    pooled = (float*)(ws + 256);               // 16 KB -> 16640
  ushort_t* W1b    = (ushort_t*)(ws + 16640);          // 256 KB -> 278784
  ushort_t* W3b    = (ushort_t*)(ws + 278784);         // 256 KB -> 540928
  ushort_t* W2r    = (ushort_t*)(ws + 540928);         // 1.125 MB -> 1720576
  ushort_t* y1Tp   = (ushort_t*)(ws + 1720576);        // 17.0 MB -> ~19.6 MB total

  k_prep  <<<5000, 256, 0, stream>>>(x, pooled, W1, W3, W2, W1b, W3b, W2r, y1Tp);
  k_router<<<16, 128, 0, stream>>>(pooled, Wr1, br1, Wr2, br2, eidx, gatew);
  k_conv1 <<<dim3(32, 16), 256, 0, stream>>>(x, W1b, eidx, y1Tp);
  k_conv23<<<dim3(32, 16), 256, 0, stream>>>(y1Tp, W2r, W3b, x, eidx, gatew, out);
}